// Round 6
// baseline (639.928 us; speedup 1.0000x reference)
//
#include <hip/hip_runtime.h>
#include <hip/hip_bf16.h>

typedef unsigned short u16;
typedef unsigned long long u64;
typedef __attribute__((ext_vector_type(8))) short bf16x8;
typedef __attribute__((ext_vector_type(4))) float f32x4;

constexpr int NN = 50000;   // nodes
constexpr int NE = 800000;  // edges
constexpr int LM = 1024;
constexpr int HC = 128;
constexpr int OC = 64;

// ---- workspace layout (bytes) ----
constexpr size_t OFF_ROWPTR = 0;          // (NN+1) int
constexpr size_t OFF_CURSOR = 200192;     // NN int
constexpr size_t OFF_PK     = 400384;     // NN u64 (count<<48 | fx32 weight sum)
constexpr size_t OFF_INCL   = 800512;     // NN int
constexpr size_t OFF_BSUM   = 1000704;    // 64 int
constexpr size_t OFF_DIS    = 1000960;    // NN float
constexpr size_t OFF_META   = 1201152;    // NE int2 (src, w-bits)
constexpr size_t OFF_WLT    = 7601408;    // LM*LM u16
constexpr size_t OFF_W1T    = 9698560;    // HC*LM u16
constexpr size_t OFF_H      = 9960704;    // NN*LM u16
constexpr size_t OFF_Y1     = 112360704;  // NN*HC u16
constexpr size_t OFF_Y3     = 125160704;  // NN*OC u16
constexpr size_t OFF_ABF    = 131560704;  // NN*LM u16 (fast path only)
constexpr size_t NEED_FAST  = OFF_ABF + (size_t)NN * LM * 2;  // ~234 MB

__device__ __forceinline__ u16 f2bf(float f) {
    union { float f; unsigned int u; } a; a.f = f;
    unsigned int u = a.u + 0x7FFFu + ((a.u >> 16) & 1u);  // RNE
    return (u16)(u >> 16);
}
__device__ __forceinline__ float bf2f(u16 v) {
    union { unsigned int u; float f; } a; a.u = ((unsigned int)v) << 16;
    return a.f;
}
__device__ __forceinline__ ushort2 pkbf(float a, float b) {
    union { __hip_bfloat162 h; ushort2 u; } cv;
    cv.h = __float22bfloat162_rn(make_float2(a, b));
    return cv.u;
}
__device__ __forceinline__ void async_copy16(u16* lds, const u16* g) {
    __builtin_amdgcn_global_load_lds(
        (const __attribute__((address_space(1))) void*)g,
        (__attribute__((address_space(3))) void*)lds, 16, 0, 0);
}
// one chunk = 8 fp32 -> 8 bf16
__device__ __forceinline__ void cvt_chunk(size_t idx, const float* __restrict__ A32,
                                          u16* __restrict__ Abf) {
    const float* src = A32 + idx * 8;
    float4 v0 = *(const float4*)(src);
    float4 v1 = *(const float4*)(src + 4);
    union { ushort2 u2[4]; bf16x8 v; } pk2;
    pk2.u2[0] = pkbf(v0.x, v0.y);
    pk2.u2[1] = pkbf(v0.z, v0.w);
    pk2.u2[2] = pkbf(v1.x, v1.y);
    pk2.u2[3] = pkbf(v1.z, v1.w);
    *(bf16x8*)(Abf + idx * 8) = pk2.v;
}

// ======= scan bodies (256-thread), shared by fused + standalone kernels ======
// segment b covers nodes [b*1024, (b+1)*1024); thread handles 4 consecutive.
__device__ __forceinline__ void scan1_body(int b, int t, const u64* __restrict__ pk,
                                           int* __restrict__ incl,
                                           int* __restrict__ bsum) {
    __shared__ int ssc[256];
    int base = b * 1024 + t * 4;
    int v[4], s = 0;
    #pragma unroll
    for (int i = 0; i < 4; i++) {
        int idx = base + i;
        v[i] = (idx < NN) ? (int)(pk[idx] >> 48) : 0;
        s += v[i];
    }
    int mytot = s;
    ssc[t] = mytot; __syncthreads();
    for (int off = 1; off < 256; off <<= 1) {
        int add = (t >= off) ? ssc[t - off] : 0;
        __syncthreads();
        ssc[t] += add;
        __syncthreads();
    }
    int prev = ssc[t] - mytot;  // exclusive prefix of this thread's 4-group
    int run = 0;
    #pragma unroll
    for (int i = 0; i < 4; i++) {
        run += v[i];
        int idx = base + i;
        if (idx < NN) incl[idx] = prev + run;
    }
    if (t == 255) bsum[b] = ssc[255];
}

__device__ __forceinline__ void scan3_body(int b, int t, const int* __restrict__ incl,
                                           const u64* __restrict__ pk,
                                           const int* __restrict__ bsum,
                                           int* __restrict__ rowptr,
                                           int* __restrict__ cursor,
                                           float* __restrict__ dis) {
    int seg = b >> 2;
    int lane = t & 63;
    int v = (lane < seg) ? bsum[lane] : 0;  // seg <= 48 < 64
    #pragma unroll
    for (int off = 32; off > 0; off >>= 1) v += __shfl_down(v, off, 64);
    int boffv = __shfl(v, 0, 64);
    int idx = b * 256 + t;
    if (idx < NN) {
        u64 p = pk[idx];
        int cnt = (int)(p >> 48);
        float deg = (float)((double)(p & 0xFFFFFFFFFFFFULL) * 2.3283064365386963e-10);
        int rp = incl[idx] - cnt + boffv;
        rowptr[idx] = rp;
        cursor[idx] = rp;
        dis[idx] = rsqrtf(1.0f + deg);
    } else if (idx == NN) {
        rowptr[NN] = NE;
    }
}

// ====== k_count: edge atomics (x4 vectorized) + Wl/W1 converts + ALL Abf =====
// blocks [0,782): edges; [782,1806): WlT; [1806,2318): W1T;
// [2318,27318) fast path: all 6.4M Abf chunks.
__global__ void k_count(const int* __restrict__ ei, const float* __restrict__ ew,
                        u64* __restrict__ pk,
                        const float* __restrict__ Wl, u16* __restrict__ WlT,
                        const float* __restrict__ W1, u16* __restrict__ W1T,
                        const float* __restrict__ A32, u16* __restrict__ Abf) {
    int b = blockIdx.x, t = threadIdx.x;
    if (b < 782) {
        int e0 = (b * 256 + t) * 4;
        if (e0 < NE) {  // NE % 4 == 0
            int4 d4 = *(const int4*)(ei + NE + e0);
            float4 w4 = *(const float4*)(ew + e0);
            atomicAdd(&pk[d4.x], (1ULL << 48) | (u64)(w4.x * 4294967296.0));
            atomicAdd(&pk[d4.y], (1ULL << 48) | (u64)(w4.y * 4294967296.0));
            atomicAdd(&pk[d4.z], (1ULL << 48) | (u64)(w4.z * 4294967296.0));
            atomicAdd(&pk[d4.w], (1ULL << 48) | (u64)(w4.w * 4294967296.0));
        }
    } else if (b < 1806) {
        __shared__ float sm[32][33];
        int bb = b - 782;
        int n0 = (bb & 31) * 32, k0 = (bb >> 5) * 32;
        int ty = t >> 5, tx = t & 31;
        #pragma unroll
        for (int i = 0; i < 4; i++)
            sm[ty + i * 8][tx] = Wl[(size_t)(k0 + ty + i * 8) * LM + n0 + tx];
        __syncthreads();
        #pragma unroll
        for (int i = 0; i < 4; i++)
            WlT[(size_t)(n0 + ty + i * 8) * LM + k0 + tx] = f2bf(sm[tx][ty + i * 8]);
    } else if (b < 2318) {
        int idx = (b - 1806) * 256 + t;  // HC*LM, output-major
        if (idx < HC * LM) {
            int o = idx >> 10, k = idx & 1023;
            W1T[idx] = f2bf(W1[(size_t)k * HC + o]);
        }
    } else {
        cvt_chunk((size_t)(b - 2318) * 256 + t, A32, Abf);
    }
}

// ====== standalone scans (slow path only) ======
__global__ void k_scan1s(const u64* __restrict__ pk, int* __restrict__ incl,
                         int* __restrict__ bsum) {
    scan1_body(blockIdx.x, threadIdx.x, pk, incl, bsum);
}
__global__ void k_scan3s(const int* __restrict__ incl, const u64* __restrict__ pk,
                         const int* __restrict__ bsum,
                         int* __restrict__ rowptr, int* __restrict__ cursor,
                         float* __restrict__ dis) {
    scan3_body(blockIdx.x, threadIdx.x, incl, pk, bsum, rowptr, cursor, dis);
}

// ====== fill CSR (x4 vectorized); dis[src] folded into weight ======
__global__ void k_fill(const int* __restrict__ ei, const float* __restrict__ ew,
                       const float* __restrict__ dis,
                       int* __restrict__ cursor, int2* __restrict__ meta) {
    int e0 = (blockIdx.x * 256 + threadIdx.x) * 4;
    if (e0 < NE) {
        int4 s4 = *(const int4*)(ei + e0);
        int4 d4 = *(const int4*)(ei + NE + e0);
        float4 w4 = *(const float4*)(ew + e0);
        int slot;
        slot = atomicAdd(&cursor[d4.x], 1);
        meta[slot] = make_int2(s4.x, __float_as_int(w4.x * dis[s4.x]));
        slot = atomicAdd(&cursor[d4.y], 1);
        meta[slot] = make_int2(s4.y, __float_as_int(w4.y * dis[s4.y]));
        slot = atomicAdd(&cursor[d4.z], 1);
        meta[slot] = make_int2(s4.z, __float_as_int(w4.z * dis[s4.z]));
        slot = atomicAdd(&cursor[d4.w], 1);
        meta[slot] = make_int2(s4.w, __float_as_int(w4.w * dis[s4.w]));
    }
}

// ======== GEMM1a (fast path): m97-style 128x128 + scan1 piggyback ===========
// blocks [0,49): scan1 (runs immediately, hidden under GEMM); [49,3185): GEMM.
__global__ __launch_bounds__(256, 2) void k_gemm1a(
    const u16* __restrict__ Abf, const u16* __restrict__ Bt, u16* __restrict__ Cout,
    const float* __restrict__ xv, const float* __restrict__ cv,
    const float* __restrict__ Wa, const float* __restrict__ Wc,
    const float* __restrict__ bl,
    const u64* __restrict__ pk, int* __restrict__ incl, int* __restrict__ bsum) {
    if (blockIdx.x < 49) {
        scan1_body(blockIdx.x, threadIdx.x, pk, incl, bsum);
        return;
    }
    __shared__ u16 lA[128 * 64];
    __shared__ u16 lB[128 * 64];
    const int tid = threadIdx.x;
    const int lane = tid & 63, wv = tid >> 6;
    const int g = blockIdx.x - 49;
    int x = g & 7, j = g >> 3;
    int bx = (j & ~7) | x;
    int by = j & 7;
    if (bx >= 391) return;  // uniform, before any barrier
    const int m0 = bx * 128, n0 = by * 128;
    const int wm = (wv >> 1) * 64, wn = (wv & 1) * 64;
    const int fr = lane & 15, qd = lane >> 4;

    f32x4 acc[4][4] = {};

    for (int kt = 0; kt < 16; kt++) {
        const int k0 = kt << 6;
        __syncthreads();
        #pragma unroll
        for (int i = 0; i < 4; i++) {
            int r0 = i * 32 + wv * 8;
            int rl = r0 + (lane >> 3);
            int slot = lane & 7;
            int k8 = slot ^ (rl & 7);
            const u16* gp = Bt + (size_t)(n0 + rl) * LM + k0 + k8 * 8;
            async_copy16(&lB[r0 * 64], gp);
        }
        #pragma unroll
        for (int i = 0; i < 4; i++) {
            int r0 = i * 32 + wv * 8;
            int rl = r0 + (lane >> 3);
            int slot = lane & 7;
            int k8 = slot ^ (rl & 7);
            int row = m0 + rl; if (row >= NN) row = NN - 1;
            const u16* gp = Abf + (size_t)row * LM + k0 + k8 * 8;
            async_copy16(&lA[r0 * 64], gp);
        }
        __syncthreads();
        #pragma unroll
        for (int s = 0; s < 2; s++) {
            const int slot = (s * 4 + qd) ^ (fr & 7);
            bf16x8 af[4], bfm[4];
            #pragma unroll
            for (int mi = 0; mi < 4; mi++)
                af[mi] = *(const bf16x8*)&lA[(wm + mi * 16 + fr) * 64 + slot * 8];
            #pragma unroll
            for (int ni = 0; ni < 4; ni++)
                bfm[ni] = *(const bf16x8*)&lB[(wn + ni * 16 + fr) * 64 + slot * 8];
            #pragma unroll
            for (int mi = 0; mi < 4; mi++)
                #pragma unroll
                for (int ni = 0; ni < 4; ni++)
                    acc[mi][ni] = __builtin_amdgcn_mfma_f32_16x16x32_bf16(
                        af[mi], bfm[ni], acc[mi][ni], 0, 0, 0);
        }
    }

    int jj[4]; float waj[4], wcj[4], blj[4];
    #pragma unroll
    for (int ni = 0; ni < 4; ni++) {
        jj[ni] = n0 + wn + ni * 16 + fr;
        waj[ni] = Wa[jj[ni]]; wcj[ni] = Wc[jj[ni]]; blj[ni] = bl[jj[ni]];
    }
    #pragma unroll
    for (int mi = 0; mi < 4; mi++)
        #pragma unroll
        for (int r = 0; r < 4; r++) {
            int row = m0 + wm + mi * 16 + qd * 4 + r;
            if (row < NN) {
                float xb = xv[row], cb = cv[row];
                #pragma unroll
                for (int ni = 0; ni < 4; ni++) {
                    float v = acc[mi][ni][r] + xb * waj[ni] + cb * wcj[ni] + blj[ni];
                    Cout[(size_t)row * LM + jj[ni]] = f2bf(fmaxf(v, 0.f));
                }
            }
        }
}

// ======== GEMM1f (fallback): 128x256 tile, fp32 A reg-prefetch staging ========
__global__ __launch_bounds__(256, 2) void k_gemm1f(
    const float* __restrict__ A32, const u16* __restrict__ Bt, u16* __restrict__ Cout,
    const float* __restrict__ xv, const float* __restrict__ cv,
    const float* __restrict__ Wa, const float* __restrict__ Wc,
    const float* __restrict__ bl) {
    __shared__ u16 lA[128 * 64];
    __shared__ u16 lB[2][128 * 64];
    const int tid = threadIdx.x;
    const int lane = tid & 63, wv = tid >> 6;
    const int bx = ((blockIdx.x >> 5) << 3) | (blockIdx.x & 7);
    const int by = (blockIdx.x >> 3) & 3;
    if (bx >= 391) return;
    const int m0 = bx * 128, n0 = by * 256;
    const int wm = (wv >> 1) * 64, wn = (wv & 1) * 64;
    const int fr = lane & 15, qd = lane >> 4;

    f32x4 acc[2][4][4] = {};

    int srl[4], sslot[4]; const float* sbase[4];
    float4 pf[8];
    #pragma unroll
    for (int i = 0; i < 4; i++) {
        int cidx = i * 256 + tid;
        srl[i] = cidx >> 3; sslot[i] = cidx & 7;
        int k8 = sslot[i] ^ (srl[i] & 7);
        int row = m0 + srl[i]; if (row >= NN) row = NN - 1;
        sbase[i] = A32 + (size_t)row * LM + k8 * 8;
    }
    #pragma unroll
    for (int i = 0; i < 4; i++) {
        pf[2 * i]     = *(const float4*)(sbase[i]);
        pf[2 * i + 1] = *(const float4*)(sbase[i] + 4);
    }

    for (int kt = 0; kt < 16; kt++) {
        const int k0 = kt << 6;
        __syncthreads();
        #pragma unroll
        for (int h = 0; h < 2; h++)
            #pragma unroll
            for (int i = 0; i < 4; i++) {
                int r0 = i * 32 + wv * 8;
                int rl = r0 + (lane >> 3);
                int slot = lane & 7;
                int k8 = slot ^ (rl & 7);
                const u16* g = Bt + (size_t)(n0 + h * 128 + rl) * LM + k0 + k8 * 8;
                async_copy16(&lB[h][r0 * 64], g);
            }
        #pragma unroll
        for (int i = 0; i < 4; i++) {
            union { ushort2 u2[4]; bf16x8 v; } pk;
            pk.u2[0] = pkbf(pf[2 * i].x, pf[2 * i].y);
            pk.u2[1] = pkbf(pf[2 * i].z, pf[2 * i].w);
            pk.u2[2] = pkbf(pf[2 * i + 1].x, pf[2 * i + 1].y);
            pk.u2[3] = pkbf(pf[2 * i + 1].z, pf[2 * i + 1].w);
            *(bf16x8*)&lA[srl[i] * 64 + sslot[i] * 8] = pk.v;
        }
        __syncthreads();
        if (kt < 15) {
            #pragma unroll
            for (int i = 0; i < 4; i++) {
                pf[2 * i]     = *(const float4*)(sbase[i] + k0 + 64);
                pf[2 * i + 1] = *(const float4*)(sbase[i] + k0 + 68);
            }
        }
        #pragma unroll
        for (int s = 0; s < 2; s++) {
            const int slot = (s * 4 + qd) ^ (fr & 7);
            bf16x8 af[4];
            #pragma unroll
            for (int mi = 0; mi < 4; mi++)
                af[mi] = *(const bf16x8*)&lA[(wm + mi * 16 + fr) * 64 + slot * 8];
            #pragma unroll
            for (int h = 0; h < 2; h++) {
                bf16x8 bfm[4];
                #pragma unroll
                for (int ni = 0; ni < 4; ni++)
                    bfm[ni] = *(const bf16x8*)&lB[h][(wn + ni * 16 + fr) * 64 + slot * 8];
                #pragma unroll
                for (int mi = 0; mi < 4; mi++)
                    #pragma unroll
                    for (int ni = 0; ni < 4; ni++)
                        acc[h][mi][ni] = __builtin_amdgcn_mfma_f32_16x16x32_bf16(
                            af[mi], bfm[ni], acc[h][mi][ni], 0, 0, 0);
            }
        }
    }

    #pragma unroll
    for (int h = 0; h < 2; h++) {
        int jj[4]; float waj[4], wcj[4], blj[4];
        #pragma unroll
        for (int ni = 0; ni < 4; ni++) {
            jj[ni] = n0 + h * 128 + wn + ni * 16 + fr;
            waj[ni] = Wa[jj[ni]]; wcj[ni] = Wc[jj[ni]]; blj[ni] = bl[jj[ni]];
        }
        #pragma unroll
        for (int mi = 0; mi < 4; mi++)
            #pragma unroll
            for (int r = 0; r < 4; r++) {
                int row = m0 + wm + mi * 16 + qd * 4 + r;
                if (row < NN) {
                    float xb = xv[row], cb = cv[row];
                    #pragma unroll
                    for (int ni = 0; ni < 4; ni++) {
                        float v = acc[h][mi][ni][r] + xb * waj[ni] + cb * wcj[ni] + blj[ni];
                        Cout[(size_t)row * LM + jj[ni]] = f2bf(fmaxf(v, 0.f));
                    }
                }
            }
    }
}

// ======== GEMM2: y1 = h @ W1, 64x128 tile; scan3 piggyback (first nscan) =====
__global__ __launch_bounds__(256) void k_gemm2(
    const u16* __restrict__ Abf, const u16* __restrict__ Bt, u16* __restrict__ Cout,
    int nscan, const int* __restrict__ incl, const u64* __restrict__ pk,
    const int* __restrict__ bsum, int* __restrict__ rowptr,
    int* __restrict__ cursor, float* __restrict__ dis) {
    if (blockIdx.x < nscan) {
        scan3_body(blockIdx.x, threadIdx.x, incl, pk, bsum, rowptr, cursor, dis);
        return;
    }
    __shared__ u16 lA[64 * 64];
    __shared__ u16 lB[128 * 64];
    const int tid = threadIdx.x;
    const int lane = tid & 63, wv = tid >> 6;
    const int m0 = (blockIdx.x - nscan) * 64;
    const int wm = (wv >> 1) * 32, wn = (wv & 1) * 64;
    const int fr = lane & 15, qd = lane >> 4;
    f32x4 acc[2][4] = {};

    for (int kt = 0; kt < 16; kt++) {
        const int k0 = kt << 6;
        __syncthreads();
        #pragma unroll
        for (int i = 0; i < 4; i++) {
            int r0 = i * 32 + wv * 8;
            int rl = r0 + (lane >> 3);
            int slot = lane & 7;
            int k8 = slot ^ (rl & 7);
            const u16* g = Bt + (size_t)rl * LM + k0 + k8 * 8;
            async_copy16(&lB[r0 * 64], g);
        }
        #pragma unroll
        for (int i = 0; i < 2; i++) {
            int r0 = i * 32 + wv * 8;
            int rl = r0 + (lane >> 3);
            int slot = lane & 7;
            int k8 = slot ^ (rl & 7);
            int row = m0 + rl; if (row >= NN) row = NN - 1;
            const u16* g = Abf + (size_t)row * LM + k0 + k8 * 8;
            async_copy16(&lA[r0 * 64], g);
        }
        __syncthreads();
        #pragma unroll
        for (int s = 0; s < 2; s++) {
            const int slot = (s * 4 + qd) ^ (fr & 7);
            bf16x8 af[2], bfm[4];
            #pragma unroll
            for (int mi = 0; mi < 2; mi++)
                af[mi] = *(const bf16x8*)&lA[(wm + mi * 16 + fr) * 64 + slot * 8];
            #pragma unroll
            for (int ni = 0; ni < 4; ni++)
                bfm[ni] = *(const bf16x8*)&lB[(wn + ni * 16 + fr) * 64 + slot * 8];
            #pragma unroll
            for (int mi = 0; mi < 2; mi++)
                #pragma unroll
                for (int ni = 0; ni < 4; ni++)
                    acc[mi][ni] = __builtin_amdgcn_mfma_f32_16x16x32_bf16(
                        af[mi], bfm[ni], acc[mi][ni], 0, 0, 0);
        }
    }
    #pragma unroll
    for (int mi = 0; mi < 2; mi++)
        #pragma unroll
        for (int r = 0; r < 4; r++) {
            int row = m0 + wm + mi * 16 + qd * 4 + r;
            if (row < NN) {
                #pragma unroll
                for (int ni = 0; ni < 4; ni++)
                    Cout[(size_t)row * HC + wn + ni * 16 + fr] = f2bf(acc[mi][ni][r]);
            }
        }
}

// ====== fused agg1 + gemm3 (W3 staged to LDS, 4-node reuse) ======
__global__ __launch_bounds__(512) void k_agg1g3(
    const u16* __restrict__ y1, const int* __restrict__ rowptr,
    const int2* __restrict__ meta, const float* __restrict__ dis,
    const float* __restrict__ b1, const float* __restrict__ W3,
    u16* __restrict__ y3) {
    __shared__ float hrow[8][HC];      // 4 KB
    __shared__ float w3s[HC * OC];     // 32 KB
    const int tid = threadIdx.x;
    const int wv = tid >> 6, lane = tid & 63;
    #pragma unroll
    for (int i = 0; i < 16; i++) w3s[i * 512 + tid] = W3[i * 512 + tid];
    int node = blockIdx.x * 8 + wv;
    float di = dis[node];
    int p0 = rowptr[node], p1 = rowptr[node + 1];
    ushort2 sv = *(const ushort2*)(y1 + (size_t)node * HC + lane * 2);
    float a0 = di * bf2f(sv.x), a1 = di * bf2f(sv.y);
    #pragma unroll 8
    for (int p = p0; p < p1; ++p) {
        int2 m = meta[p];
        float nm = __int_as_float(m.y);
        ushort2 v = *(const ushort2*)(y1 + (size_t)m.x * HC + lane * 2);
        a0 += nm * bf2f(v.x);
        a1 += nm * bf2f(v.y);
    }
    a0 = fmaxf(di * a0 + b1[lane * 2], 0.f);
    a1 = fmaxf(di * a1 + b1[lane * 2 + 1], 0.f);
    hrow[wv][lane * 2] = a0;
    hrow[wv][lane * 2 + 1] = a1;
    __syncthreads();
    if (wv < 2) {
        const int nb = wv * 4;
        float c0 = 0.f, c1 = 0.f, c2 = 0.f, c3 = 0.f;
        #pragma unroll 4
        for (int k = 0; k < HC; ++k) {
            float w = w3s[k * OC + lane];
            c0 += hrow[nb][k] * w;
            c1 += hrow[nb + 1][k] * w;
            c2 += hrow[nb + 2][k] * w;
            c3 += hrow[nb + 3][k] * w;
        }
        size_t base = (size_t)(blockIdx.x * 8 + nb) * OC + lane;
        y3[base]          = f2bf(c0);
        y3[base + OC]     = f2bf(c1);
        y3[base + 2 * OC] = f2bf(c2);
        y3[base + 3 * OC] = f2bf(c3);
    }
}

// ================= aggregation 3 =================
__global__ __launch_bounds__(256) void k_agg3(
    const u16* __restrict__ y3, const int* __restrict__ rowptr,
    const int2* __restrict__ meta, const float* __restrict__ dis,
    const float* __restrict__ b3, float* __restrict__ outp) {
    int node = blockIdx.x * 4 + (threadIdx.x >> 6);
    int lane = threadIdx.x & 63;
    if (node >= NN) return;
    float di = dis[node];
    int p0 = rowptr[node], p1 = rowptr[node + 1];
    float a = di * bf2f(y3[(size_t)node * OC + lane]);
    #pragma unroll 8
    for (int p = p0; p < p1; ++p) {
        int2 m = meta[p];
        a += __int_as_float(m.y) * bf2f(y3[(size_t)m.x * OC + lane]);
    }
    outp[(size_t)node * OC + lane] = di * a + b3[lane];
}

extern "C" void kernel_launch(void* const* d_in, const int* in_sizes, int n_in,
                              void* d_out, int out_size, void* d_ws, size_t ws_size,
                              hipStream_t stream) {
    const float* x    = (const float*)d_in[0];
    const float* xout = (const float*)d_in[1];
    const float* c    = (const float*)d_in[2];
    const int*   ei   = (const int*)d_in[3];
    const float* ew   = (const float*)d_in[4];
    const float* Wa   = (const float*)d_in[5];
    const float* Wc   = (const float*)d_in[6];
    const float* Wl   = (const float*)d_in[7];
    const float* bl   = (const float*)d_in[8];
    const float* W1   = (const float*)d_in[9];
    const float* b1   = (const float*)d_in[10];
    const float* W3   = (const float*)d_in[11];
    const float* b3   = (const float*)d_in[12];
    float* outp = (float*)d_out;

    char* ws = (char*)d_ws;
    int*   rowptr = (int*)(ws + OFF_ROWPTR);
    int*   cursor = (int*)(ws + OFF_CURSOR);
    u64*   pk     = (u64*)(ws + OFF_PK);
    int*   incl   = (int*)(ws + OFF_INCL);
    int*   bsum   = (int*)(ws + OFF_BSUM);
    float* dis    = (float*)(ws + OFF_DIS);
    int2*  meta   = (int2*)(ws + OFF_META);
    u16*   WlT    = (u16*)(ws + OFF_WLT);
    u16*   W1T    = (u16*)(ws + OFF_W1T);
    u16*   hbuf   = (u16*)(ws + OFF_H);
    u16*   y1     = (u16*)(ws + OFF_Y1);
    u16*   y3     = (u16*)(ws + OFF_Y3);
    u16*   Abf    = (u16*)(ws + OFF_ABF);

    const bool fast = (ws_size >= NEED_FAST);

    // pk zero via memset (must precede count atomics)
    hipMemsetAsync(pk, 0, (size_t)NN * sizeof(u64), stream);

    if (fast) {
        // 7-dispatch chain; scans hidden inside the GEMM launches.
        k_count<<<27318, 256, 0, stream>>>(ei, ew, pk, Wl, WlT, W1, W1T, xout, Abf);
        k_gemm1a<<<49 + 392 * 8, 256, 0, stream>>>(Abf, WlT, hbuf, x, c, Wa, Wc, bl,
                                                   pk, incl, bsum);
        k_gemm2<<<196 + 782, 256, 0, stream>>>(hbuf, W1T, y1, 196, incl, pk, bsum,
                                               rowptr, cursor, dis);
        k_fill<<<782, 256, 0, stream>>>(ei, ew, dis, cursor, meta);
    } else {
        k_count<<<2318, 256, 0, stream>>>(ei, ew, pk, Wl, WlT, W1, W1T, xout, Abf);
        k_scan1s<<<49, 256, 0, stream>>>(pk, incl, bsum);
        k_scan3s<<<196, 256, 0, stream>>>(incl, pk, bsum, rowptr, cursor, dis);
        k_fill<<<782, 256, 0, stream>>>(ei, ew, dis, cursor, meta);
        k_gemm1f<<<49 * 32, 256, 0, stream>>>(xout, WlT, hbuf, x, c, Wa, Wc, bl);
        k_gemm2<<<782, 256, 0, stream>>>(hbuf, W1T, y1, 0, incl, pk, bsum,
                                         rowptr, cursor, dis);
    }
    // conv1 aggregation + bias + relu + conv3 linear (fused)
    k_agg1g3<<<6250, 512, 0, stream>>>(y1, rowptr, meta, dis, b1, W3, y3);
    // conv3 aggregation + bias -> out
    k_agg3<<<12500, 256, 0, stream>>>(y3, rowptr, meta, dis, b3, outp);
}